// Round 5
// baseline (88.213 us; speedup 1.0000x reference)
//
#include <hip/hip_runtime.h>

#define N_ 256
#define C_ 2048
#define HW_ 49
#define CPB 64
#define NCC (C_/CPB)   // 32

// local-channel base in sx: 70 channels (3 halo low, 64 main, 3 halo high).
// Main chunk starts at 148 (16B-aligned for float4); halo-low at 0, gap at 147.
#define CHB(lc) ((lc) * HW_ + ((lc) >= 3 ? 1 : 0))

// ---------------- kernel 1: per-chunk channel-pool partials ----------------
__global__ __launch_bounds__(256) void k_poolc(const float* __restrict__ x,
                                               float* __restrict__ psum,
                                               float* __restrict__ pmax) {
  const int cc = blockIdx.x, n = blockIdx.y;
  const int t = threadIdx.x;
  __shared__ float sx[CPB * HW_];      // 3136
  __shared__ float part_s[HW_][5];
  __shared__ float part_m[HW_][5];

  const float4* xv = (const float4*)(x + ((size_t)n * C_ + (size_t)cc * CPB) * HW_);
  for (int v = t; v < 784; v += 256) {
    float4 q = xv[v];
    sx[v * 4 + 0] = q.x; sx[v * 4 + 1] = q.y;
    sx[v * 4 + 2] = q.z; sx[v * 4 + 3] = q.w;
  }
  __syncthreads();

  if (t < 245) {
    int hw = t / 5, s = t % 5;
    float sm = 0.f, mx = -3.4e38f;
    #pragma unroll
    for (int j = 0; j < 13; ++j) {
      int c = s * 13 + j;
      if (c < CPB) {
        float a = sx[c * HW_ + hw];
        sm += a; mx = fmaxf(mx, a);
      }
    }
    part_s[hw][s] = sm; part_m[hw][s] = mx;
  }
  __syncthreads();

  if (t < HW_) {
    float sm = 0.f, mx = -3.4e38f;
    #pragma unroll
    for (int s = 0; s < 5; ++s) { sm += part_s[t][s]; mx = fmaxf(mx, part_m[t][s]); }
    size_t o = ((size_t)n * NCC + cc) * HW_ + t;
    psum[o] = sm; pmax[o] = mx;
  }
}

// ---------------- kernel 2: reduce chunks, compute g_hw gate per n ----------------
__global__ __launch_bounds__(64) void k_ghw(const float* __restrict__ psum,
                                            const float* __restrict__ pmax,
                                            const float* __restrict__ cw,
                                            const float* __restrict__ cb,
                                            const float* __restrict__ bnw,
                                            const float* __restrict__ bnb,
                                            const float* __restrict__ bnrm,
                                            const float* __restrict__ bnrv,
                                            float* __restrict__ ghw) {
  const int n = blockIdx.x;
  const int t = threadIdx.x;
  __shared__ float p2c[2][13][13];
  __shared__ float s_cw[98];

  for (int i = t; i < 2 * 13 * 13; i += 64) ((float*)p2c)[i] = 0.f;
  for (int i = t; i < 98; i += 64) s_cw[i] = cw[i];
  __syncthreads();

  if (t < HW_) {
    float sm = 0.f, mx = -3.4e38f;
    const float* ps = psum + (size_t)n * NCC * HW_ + t;
    const float* pm = pmax + (size_t)n * NCC * HW_ + t;
    for (int cc = 0; cc < NCC; ++cc) {
      sm += ps[cc * HW_];
      mx = fmaxf(mx, pm[cc * HW_]);
    }
    p2c[0][t / 7 + 3][t % 7 + 3] = sm * (1.f / C_);
    p2c[1][t / 7 + 3][t % 7 + 3] = mx;
  }
  __syncthreads();

  if (t < HW_) {
    int a = t / 7, b = t % 7;
    float y = cb[0];
    #pragma unroll
    for (int i2 = 0; i2 < 2; ++i2)
      #pragma unroll
      for (int p = 0; p < 7; ++p)
        #pragma unroll
        for (int q = 0; q < 7; ++q)
          y += p2c[i2][a + p][b + q] * s_cw[i2 * 49 + p * 7 + q];
    float sc = bnw[0] * rsqrtf(bnrv[0] + 1e-5f);
    y = (y - bnrm[0]) * sc + bnb[0];
    y = fmaxf(y, 0.f);
    ghw[n * HW_ + t] = 1.f / (1.f + __expf(-y));
  }
}

// ---------------- kernel 3: W/H pools, g_ch/g_cw gates, fused multiply ----------------
// LDS: sx[3432] + pool[2240] + gch[448] + gcw[448] + s_cw[98] + s_ghw[49]
//    = 6715 floats = 26.86 KB  -> 6 blocks/CU (161.2 KB of 160 KB*... fits: 6*26860=161160 <= 163840)
__global__ __launch_bounds__(256, 6) void k_main(const float* __restrict__ x,
    const float* __restrict__ ghw,
    const float* __restrict__ cw, const float* __restrict__ cb,
    const float* __restrict__ bnw, const float* __restrict__ bnb,
    const float* __restrict__ bnrm, const float* __restrict__ bnrv,
    float* __restrict__ out) {
  const int cc = blockIdx.x;
  const int n  = (N_ - 1) - blockIdx.y;
  const int c0 = cc * CPB;
  const int t  = threadIdx.x;

  __shared__ __align__(16) float sx[3432];    // 70ch x 49 (+gap at 147)
  __shared__ __align__(16) float pool[2240];  // [2][2][70][8]: 32B rows, b128-readable
  __shared__ float gch[448];                  // [64][7]
  __shared__ float gcw[448];
  __shared__ float s_cw[98];
  __shared__ float s_ghw[49];

  const int conv = t & 1, i2 = (t >> 1) & 1, cl = t >> 2;
  const int bi = 1 + conv;
  const float cb0 = cb[0];
  const float sc_bn = bnw[bi] * rsqrtf(bnrv[bi] + 1e-5f);
  const float rm_bn = bnrm[bi];
  const float sh_bn = bnb[bi];

  // ---- phase 0: stage ----
  for (int i = t; i < 98; i += 256) s_cw[i] = cw[i];
  if (t < HW_) s_ghw[t] = ghw[n * HW_ + t];
  // halo channels (scalar, long latency — issue early)
  for (int i = t; i < 2 * 3 * HW_; i += 256) {
    int side = i / 147, off = i % 147;
    int lc = side ? (67 + off / HW_) : (off / HW_);
    int c = c0 - 3 + lc;
    float vv = 0.f;
    if (c >= 0 && c < C_) vv = x[((size_t)n * C_ + c) * HW_ + off % HW_];
    sx[CHB(lc) + off % HW_] = vv;
  }
  const float4* xv = (const float4*)(x + ((size_t)n * C_ + c0) * HW_);
  float4* sxv = (float4*)(sx + 148);
  for (int v = t; v < 784; v += 256) sxv[v] = xv[v];
  __syncthreads();

  // ---- phase 1: W-pools / H-pools for all 70 local channels ----
  for (int i = t; i < 70 * 7; i += 256) {
    int lc = i / 7, k = i % 7;
    int base = CHB(lc);
    float s1 = 0.f, m1 = -3.4e38f, s2 = 0.f, m2 = -3.4e38f;
    #pragma unroll
    for (int j = 0; j < 7; ++j) {
      float a = sx[base + k * 7 + j];   // h=k, vary w  -> W-reduction (g_ch input)
      s1 += a; m1 = fmaxf(m1, a);
      float b = sx[base + j * 7 + k];   // w=k, vary h  -> H-reduction (g_cw input)
      s2 += b; m2 = fmaxf(m2, b);
    }
    pool[((0 * 2 + 0) * 70 + lc) * 8 + k] = s1 * (1.f / 7.f);
    pool[((0 * 2 + 1) * 70 + lc) * 8 + k] = m1;
    pool[((1 * 2 + 0) * 70 + lc) * 8 + k] = s2 * (1.f / 7.f);
    pool[((1 * 2 + 1) * 70 + lc) * 8 + k] = m2;
  }
  __syncthreads();

  // ---- phase 2: conv via b128 register rows; thread = (conv, i2, cl) ----
  {
    const float* Wb = s_cw + i2 * 49;
    const float* Pb = pool + ((conv * 2 + i2) * 70 + cl) * 8;
    float acc[7] = {0.f, 0.f, 0.f, 0.f, 0.f, 0.f, 0.f};
    #pragma unroll
    for (int p = 0; p < 7; ++p) {
      float4 r0 = *(const float4*)(Pb + p * 8);
      float4 r1 = *(const float4*)(Pb + p * 8 + 4);
      float row[7] = {r0.x, r0.y, r0.z, r0.w, r1.x, r1.y, r1.z};
      #pragma unroll
      for (int q = 0; q < 7; ++q) {
        float wv = Wb[p * 7 + q];
        #pragma unroll
        for (int k = 0; k < 7; ++k) {
          int c = k + q - 3;                 // compile-time after unroll
          if (c >= 0 && c < 7) acc[k] += row[c] * wv;
        }
      }
    }
    float fsum[7];
    #pragma unroll
    for (int k = 0; k < 7; ++k) fsum[k] = acc[k] + __shfl_xor(acc[k], 2, 64);
    if (i2 == 0) {
      float* gp = (conv ? gcw : gch) + cl * 7;
      #pragma unroll
      for (int k = 0; k < 7; ++k) {
        float y = (fsum[k] + cb0 - rm_bn) * sc_bn + sh_bn;
        y = fmaxf(y, 0.f);
        gp[k] = 1.f / (1.f + __expf(-y));
      }
    }
  }
  __syncthreads();

  // ---- phase 3: fused multiply, LDS re-read (b128), float4 stores ----
  float4* outv = (float4*)(out + ((size_t)n * C_ + c0) * HW_);
  for (int v = t; v < 784; v += 256) {
    float4 q = sxv[v];
    int e0 = v * 4;
    int cj = e0 / 49;
    int hw0 = e0 - cj * 49;
    float r0 = q.x, r1 = q.y, r2 = q.z, r3 = q.w;
    {
      int hw = hw0;
      int cjj = cj + (hw >= 49); hw -= (hw >= 49) ? 49 : 0;
      int h = (hw * 37) >> 8, w2 = hw - h * 7;
      r0 *= (s_ghw[hw] + gch[cjj * 7 + h] + gcw[cjj * 7 + w2]) * (1.f / 3.f);
    }
    {
      int hw = hw0 + 1;
      int cjj = cj + (hw >= 49); hw -= (hw >= 49) ? 49 : 0;
      int h = (hw * 37) >> 8, w2 = hw - h * 7;
      r1 *= (s_ghw[hw] + gch[cjj * 7 + h] + gcw[cjj * 7 + w2]) * (1.f / 3.f);
    }
    {
      int hw = hw0 + 2;
      int cjj = cj + (hw >= 49); hw -= (hw >= 49) ? 49 : 0;
      int h = (hw * 37) >> 8, w2 = hw - h * 7;
      r2 *= (s_ghw[hw] + gch[cjj * 7 + h] + gcw[cjj * 7 + w2]) * (1.f / 3.f);
    }
    {
      int hw = hw0 + 3;
      int cjj = cj + (hw >= 49); hw -= (hw >= 49) ? 49 : 0;
      int h = (hw * 37) >> 8, w2 = hw - h * 7;
      r3 *= (s_ghw[hw] + gch[cjj * 7 + h] + gcw[cjj * 7 + w2]) * (1.f / 3.f);
    }
    outv[v] = make_float4(r0, r1, r2, r3);
  }
}

extern "C" void kernel_launch(void* const* d_in, const int* in_sizes, int n_in,
                              void* d_out, int out_size, void* d_ws, size_t ws_size,
                              hipStream_t stream) {
  const float* x    = (const float*)d_in[0];
  const float* cw   = (const float*)d_in[1];
  const float* cb   = (const float*)d_in[2];
  const float* bnw  = (const float*)d_in[3];
  const float* bnb  = (const float*)d_in[4];
  const float* bnrm = (const float*)d_in[5];
  const float* bnrv = (const float*)d_in[6];
  float* out = (float*)d_out;

  float* psum = (float*)d_ws;                       // N*32*49
  float* pmax = psum + (size_t)N_ * NCC * HW_;      // N*32*49
  float* ghw  = pmax + (size_t)N_ * NCC * HW_;      // N*49

  k_poolc<<<dim3(NCC, N_), 256, 0, stream>>>(x, psum, pmax);
  k_ghw<<<dim3(N_), 64, 0, stream>>>(psum, pmax, cw, cb, bnw, bnb, bnrm, bnrv, ghw);
  k_main<<<dim3(NCC, N_), 256, 0, stream>>>(x, ghw, cw, cb, bnw, bnb, bnrm, bnrv, out);
}